// Round 5
// baseline (841.412 us; speedup 1.0000x reference)
//
#include <hip/hip_runtime.h>

#define HIDDEN 128
#define NLAYERS 4

typedef __attribute__((ext_vector_type(8))) short short8;
typedef __attribute__((ext_vector_type(4))) float f32x4;

__device__ __forceinline__ ushort f2bf(float f) {
    uint x = __builtin_bit_cast(uint, f);
    return (ushort)((x + 0x7fffu + ((x >> 16) & 1u)) >> 16);
}
__device__ __forceinline__ float bf2f(ushort u) {
    uint x = ((uint)u) << 16;
    return __builtin_bit_cast(float, x);
}
__device__ __forceinline__ float bflo(uint u) {
    return __builtin_bit_cast(float, u << 16);
}
__device__ __forceinline__ float bfhi(uint u) {
    return __builtin_bit_cast(float, u & 0xffff0000u);
}

// ---------------- CSR build ----------------

__global__ void hist_kernel(const int* __restrict__ dst, int* __restrict__ counts, int E) {
    int e = blockIdx.x * blockDim.x + threadIdx.x;
    if (e < E) atomicAdd(&counts[dst[e]], 1);
}

// single-block scan, 4 elements/thread (4096/chunk)
__global__ __launch_bounds__(1024) void scan_kernel(const int* __restrict__ counts,
                                                    int* __restrict__ offsets,
                                                    int* __restrict__ wpos, int n) {
    __shared__ int wsum[16];
    __shared__ int carry_s;
    const int t = threadIdx.x, wv = t >> 6, ln = t & 63;
    if (t == 0) carry_s = 0;
    __syncthreads();
    for (int base = 0; base < n; base += 4096) {
        const int i = base + t * 4;
        int4 c = {0, 0, 0, 0};
        if (i + 3 < n) {
            c = *(const int4*)(counts + i);
        } else {
            if (i < n)     c.x = counts[i];
            if (i + 1 < n) c.y = counts[i + 1];
            if (i + 2 < n) c.z = counts[i + 2];
            if (i + 3 < n) c.w = counts[i + 3];
        }
        const int tsum = c.x + c.y + c.z + c.w;
        int s = tsum;
#pragma unroll
        for (int off = 1; off < 64; off <<= 1) {
            int x = __shfl_up(s, off, 64);
            if (ln >= off) s += x;
        }
        if (ln == 63) wsum[wv] = s;
        __syncthreads();
        if (t < 16) {
            int x = wsum[t];
#pragma unroll
            for (int off = 1; off < 16; off <<= 1) {
                int y = __shfl_up(x, off, 16);
                if ((t & 15) >= off) x += y;
            }
            wsum[t] = x;
        }
        __syncthreads();
        const int wbase = (wv ? wsum[wv - 1] : 0) + carry_s;
        const int excl = wbase + s - tsum;
        int4 o;
        o.x = excl;
        o.y = excl + c.x;
        o.z = o.y + c.y;
        o.w = o.z + c.z;
        if (i + 3 < n) {
            *(int4*)(offsets + i) = o;
            *(int4*)(wpos + i) = o;
        } else {
            if (i < n)     { offsets[i] = o.x;     wpos[i] = o.x; }
            if (i + 1 < n) { offsets[i + 1] = o.y; wpos[i + 1] = o.y; }
            if (i + 2 < n) { offsets[i + 2] = o.z; wpos[i + 2] = o.z; }
            if (i + 3 < n) { offsets[i + 3] = o.w; wpos[i + 3] = o.w; }
        }
        __syncthreads();
        if (t == 0) carry_s += wsum[15];
        __syncthreads();
    }
    if (t == 0) offsets[n] = carry_s;
}

__global__ void fill_kernel(const int* __restrict__ src, const int* __restrict__ dst,
                            int* __restrict__ wpos, int* __restrict__ csr_src,
                            int* __restrict__ csr_eid, int E) {
    int e = blockIdx.x * blockDim.x + threadIdx.x;
    if (e < E) {
        int d = dst[e];
        int p = atomicAdd(&wpos[d], 1);
        csr_src[p] = src[e];
        csr_eid[p] = e;
    }
}

// eattr_csr[p][:] = edge_attr[csr_eid[p]][:]  (f32, 64B/edge), 4 threads/edge
__global__ void ereorder_kernel(const int* __restrict__ csr_eid,
                                const float4* __restrict__ edge_attr,
                                float4* __restrict__ eattr_csr, int total4) {
    int i = blockIdx.x * blockDim.x + threadIdx.x;
    if (i < total4) {
        int p = i >> 2, part = i & 3;
        int eid = csr_eid[p];
        eattr_csr[i] = edge_attr[(size_t)eid * 4 + part];
    }
}

// ---------------- init / weight prep ----------------

__global__ void h16init_kernel(const float* __restrict__ x, ushort* __restrict__ h16, int total4) {
    int i = blockIdx.x * blockDim.x + threadIdx.x;
    if (i < total4) {
        float4 v = ((const float4*)x)[i];
        uint2 o;
        o.x = (uint)f2bf(v.x) | ((uint)f2bf(v.y) << 16);
        o.y = (uint)f2bf(v.z) | ((uint)f2bf(v.w) << 16);
        ((uint2*)h16)[i] = o;
    }
}

__global__ void wconv_kernel(const float* __restrict__ W1, const float* __restrict__ W2,
                             ushort* __restrict__ Wt) {
    int i = blockIdx.x * blockDim.x + threadIdx.x;  // < 4*2*128*128
    int l = i >> 15;
    int m = (i >> 14) & 1;
    int nn = (i >> 7) & 127;
    int kk = i & 127;
    const float* W = m ? W2 : W1;
    Wt[i] = f2bf(W[l * 16384 + kk * 128 + nn]);
}

// ---------------- aggregation: recompute ea in-flight ----------------
// wave = node; half-wave = edge; lane = 4 channels.
// z0 = bf16(h32 + sum_in relu(h16[src] + (eattr_csr@We + be)))
__global__ __launch_bounds__(256) void agg_kernel(const ushort* __restrict__ h16,
                                                  const float* __restrict__ h32,
                                                  const int* __restrict__ csr_src,
                                                  const float* __restrict__ eattr_csr,
                                                  const int* __restrict__ offsets,
                                                  const float* __restrict__ We,
                                                  const float* __restrict__ be,
                                                  ushort* __restrict__ z0, int n) {
    const int v = blockIdx.x * 4 + (threadIdx.x >> 6);
    if (v >= n) return;
    const int l  = threadIdx.x & 63;
    const int hw = l >> 5;            // half-wave owns one edge
    const int q  = l & 31;
    const int c0 = q * 4;             // 4 channels per lane

    float4 wec[16];
#pragma unroll
    for (int f = 0; f < 16; ++f) wec[f] = *(const float4*)(We + f * HIDDEN + c0);
    const float4 bec = *(const float4*)(be + c0);

    const int e0 = offsets[v], e1 = offsets[v + 1];
    float4 acc = {0.f, 0.f, 0.f, 0.f};

    for (int it = e0; it < e1; it += 2) {
        const int e = it + hw;
        const float vm = (e < e1) ? 1.f : 0.f;
        const int ec = (e < e1) ? e : (e1 - 1);
        const int s = csr_src[ec];
        const float4* fp = (const float4*)(eattr_csr + (size_t)ec * 16);
        const float4 f0 = fp[0], f1 = fp[1], f2 = fp[2], f3 = fp[3];
        const uint2 hv = *(const uint2*)(h16 + (size_t)s * HIDDEN + c0);
        float4 m;
        m.x = bec.x + bflo(hv.x);
        m.y = bec.y + bfhi(hv.x);
        m.z = bec.z + bflo(hv.y);
        m.w = bec.w + bfhi(hv.y);
#define FMA_COL(mc, wc)                                                   \
        mc = fmaf(f0.x, wec[0].wc,  mc); mc = fmaf(f0.y, wec[1].wc,  mc); \
        mc = fmaf(f0.z, wec[2].wc,  mc); mc = fmaf(f0.w, wec[3].wc,  mc); \
        mc = fmaf(f1.x, wec[4].wc,  mc); mc = fmaf(f1.y, wec[5].wc,  mc); \
        mc = fmaf(f1.z, wec[6].wc,  mc); mc = fmaf(f1.w, wec[7].wc,  mc); \
        mc = fmaf(f2.x, wec[8].wc,  mc); mc = fmaf(f2.y, wec[9].wc,  mc); \
        mc = fmaf(f2.z, wec[10].wc, mc); mc = fmaf(f2.w, wec[11].wc, mc); \
        mc = fmaf(f3.x, wec[12].wc, mc); mc = fmaf(f3.y, wec[13].wc, mc); \
        mc = fmaf(f3.z, wec[14].wc, mc); mc = fmaf(f3.w, wec[15].wc, mc)
        FMA_COL(m.x, x);
        FMA_COL(m.y, y);
        FMA_COL(m.z, z);
        FMA_COL(m.w, w);
#undef FMA_COL
        acc.x = fmaf(vm, fmaxf(m.x, 0.f), acc.x);
        acc.y = fmaf(vm, fmaxf(m.y, 0.f), acc.y);
        acc.z = fmaf(vm, fmaxf(m.z, 0.f), acc.z);
        acc.w = fmaf(vm, fmaxf(m.w, 0.f), acc.w);
    }

    acc.x += __shfl_xor(acc.x, 32, 64);
    acc.y += __shfl_xor(acc.y, 32, 64);
    acc.z += __shfl_xor(acc.z, 32, 64);
    acc.w += __shfl_xor(acc.w, 32, 64);

    if (hw == 0) {
        const float4 hvv = *(const float4*)(h32 + (size_t)v * HIDDEN + c0);
        uint2 o;
        o.x = (uint)f2bf(hvv.x + acc.x) | ((uint)f2bf(hvv.y + acc.y) << 16);
        o.y = (uint)f2bf(hvv.z + acc.z) | ((uint)f2bf(hvv.w + acc.w) << 16);
        *(uint2*)(z0 + (size_t)v * HIDDEN + c0) = o;
    }
}

// ---------------- fused MFMA MLP + in-register LayerNorm + residual ----------------
__global__ __launch_bounds__(256, 3) void mlp_kernel(const ushort* __restrict__ z0,
                                                     float* __restrict__ h32,
                                                     ushort* __restrict__ h16,
                                                     const ushort* __restrict__ W1t,
                                                     const ushort* __restrict__ W2t,
                                                     const float* __restrict__ b1,
                                                     const float* __restrict__ b2,
                                                     const float* __restrict__ lng,
                                                     const float* __restrict__ lnb,
                                                     int n, int write_h16) {
    __shared__ char smem[49152];  // [0,32K): weights (swizzled bf16) ; [32K,48K): act
    const int t = threadIdx.x, l = t & 63, w = t >> 6;
    const int lm = l & 15, lg = l >> 4;
    const int r0 = blockIdx.x * 64;

#pragma unroll
    for (int j = 0; j < 8; ++j) {
        int idx = t + j * 256;
        int byte = (idx * 16) ^ (((idx >> 4) & 7) << 4);
        *(short8*)(smem + byte) = *(const short8*)(W1t + idx * 8);
    }

    float b1v[8], b2v[8], lngv[8], lnbv[8];
#pragma unroll
    for (int nt = 0; nt < 8; ++nt) {
        int col = nt * 16 + lm;
        b1v[nt] = b1[col]; b2v[nt] = b2[col];
        lngv[nt] = lng[col]; lnbv[nt] = lnb[col];
    }

    short8 a[4];
    {
        int arow = r0 + w * 16 + lm;
        if (arow >= n) arow = n - 1;
        const ushort* zp = z0 + (size_t)arow * HIDDEN + lg * 8;
#pragma unroll
        for (int kk = 0; kk < 4; ++kk) a[kk] = *(const short8*)(zp + kk * 32);
    }
    __syncthreads();

    f32x4 acc[8];
#pragma unroll
    for (int nt = 0; nt < 8; ++nt) {
        f32x4 c = {0.f, 0.f, 0.f, 0.f};
#pragma unroll
        for (int kk = 0; kk < 4; ++kk) {
            int nrow = nt * 16 + lm;
            int byte = (nrow * 256 + kk * 64 + lg * 16) ^ ((nrow & 7) << 4);
            short8 b = *(const short8*)(smem + byte);
            c = __builtin_amdgcn_mfma_f32_16x16x32_bf16(a[kk], b, c, 0, 0, 0);
        }
        acc[nt] = c;
    }

#pragma unroll
    for (int nt = 0; nt < 8; ++nt) {
        int col = nt * 16 + lm;
#pragma unroll
        for (int j = 0; j < 4; ++j) {
            int rw = w * 16 + lg * 4 + j;
            int byte = (rw * 256 + col * 2) ^ ((rw & 7) << 4);
            *(ushort*)(smem + 32768 + byte) = f2bf(fmaxf(acc[nt][j] + b1v[nt], 0.f));
        }
    }
    __syncthreads();

#pragma unroll
    for (int j = 0; j < 8; ++j) {
        int idx = t + j * 256;
        int byte = (idx * 16) ^ (((idx >> 4) & 7) << 4);
        *(short8*)(smem + byte) = *(const short8*)(W2t + idx * 8);
    }
    short8 a2[4];
    {
        int rw = w * 16 + lm;
#pragma unroll
        for (int kk = 0; kk < 4; ++kk) {
            int byte = (rw * 256 + kk * 64 + lg * 16) ^ ((rw & 7) << 4);
            a2[kk] = *(const short8*)(smem + 32768 + byte);
        }
    }
    __syncthreads();

    f32x4 acc2[8];
#pragma unroll
    for (int nt = 0; nt < 8; ++nt) {
        f32x4 c = {0.f, 0.f, 0.f, 0.f};
#pragma unroll
        for (int kk = 0; kk < 4; ++kk) {
            int nrow = nt * 16 + lm;
            int byte = (nrow * 256 + kk * 64 + lg * 16) ^ ((nrow & 7) << 4);
            short8 b = *(const short8*)(smem + byte);
            c = __builtin_amdgcn_mfma_f32_16x16x32_bf16(a2[kk], b, c, 0, 0, 0);
        }
        acc2[nt] = c;
    }

    float val[8][4];
#pragma unroll
    for (int nt = 0; nt < 8; ++nt)
#pragma unroll
        for (int j = 0; j < 4; ++j) val[nt][j] = acc2[nt][j] + b2v[nt];

    float mu[4], rs[4];
#pragma unroll
    for (int j = 0; j < 4; ++j) {
        float s = 0.f;
#pragma unroll
        for (int nt = 0; nt < 8; ++nt) s += val[nt][j];
        s += __shfl_xor(s, 1, 64); s += __shfl_xor(s, 2, 64);
        s += __shfl_xor(s, 4, 64); s += __shfl_xor(s, 8, 64);
        mu[j] = s * (1.f / 128.f);
        float d2 = 0.f;
#pragma unroll
        for (int nt = 0; nt < 8; ++nt) {
            float d = val[nt][j] - mu[j];
            d2 = fmaf(d, d, d2);
        }
        d2 += __shfl_xor(d2, 1, 64); d2 += __shfl_xor(d2, 2, 64);
        d2 += __shfl_xor(d2, 4, 64); d2 += __shfl_xor(d2, 8, 64);
        rs[j] = rsqrtf(d2 * (1.f / 128.f) + 1e-5f);
    }

#pragma unroll
    for (int j = 0; j < 4; ++j) {
        int grow = r0 + w * 16 + lg * 4 + j;
        if (grow < n) {
#pragma unroll
            for (int nt = 0; nt < 8; ++nt) {
                int col = nt * 16 + lm;
                size_t o = (size_t)grow * HIDDEN + col;
                float y = fmaxf((val[nt][j] - mu[j]) * rs[j] * lngv[nt] + lnbv[nt], 0.f) + h32[o];
                h32[o] = y;
                if (write_h16) h16[o] = f2bf(y);
            }
        }
    }
}

// ---------------- launch ----------------

extern "C" void kernel_launch(void* const* d_in, const int* in_sizes, int n_in,
                              void* d_out, int out_size, void* d_ws, size_t ws_size,
                              hipStream_t stream) {
    const float* x     = (const float*)d_in[0];
    const int*   ei    = (const int*)d_in[2];
    const float* eattr = (const float*)d_in[3];
    const float* We    = (const float*)d_in[4];
    const float* be    = (const float*)d_in[5];
    const float* W1    = (const float*)d_in[6];
    const float* b1    = (const float*)d_in[7];
    const float* W2    = (const float*)d_in[8];
    const float* b2    = (const float*)d_in[9];
    const float* lng   = (const float*)d_in[10];
    const float* lnb   = (const float*)d_in[11];
    float* h32 = (float*)d_out;

    const int n = in_sizes[0] / HIDDEN;
    const int E = in_sizes[2] / 2;
    const int* src = ei;
    const int* dst = ei + E;

    size_t off = 0;
    auto take = [&](size_t bytes) {
        void* p = (char*)d_ws + off;
        off += (bytes + 255) & ~(size_t)255;
        return p;
    };
    ushort* z0        = (ushort*)take((size_t)n * HIDDEN * 2);
    ushort* h16       = (ushort*)take((size_t)n * HIDDEN * 2);
    ushort* Wt        = (ushort*)take((size_t)NLAYERS * 2 * HIDDEN * HIDDEN * 2);
    int*    counts    = (int*)take((size_t)n * 4);
    int*    offsets   = (int*)take(((size_t)n + 1) * 4);
    int*    wpos      = (int*)take((size_t)n * 4);
    int*    csr_src   = (int*)take((size_t)E * 4);
    int*    csr_eid   = (int*)take((size_t)E * 4);
    float*  eattr_csr = (float*)take((size_t)E * 16 * 4);

    hipMemcpyAsync(h32, x, (size_t)n * HIDDEN * 4, hipMemcpyDeviceToDevice, stream);
    h16init_kernel<<<((n * HIDDEN / 4) + 255) / 256, 256, 0, stream>>>(x, h16, n * HIDDEN / 4);
    wconv_kernel<<<(NLAYERS * 2 * HIDDEN * HIDDEN) / 256, 256, 0, stream>>>(W1, W2, Wt);

    hipMemsetAsync(counts, 0, (size_t)n * 4, stream);
    int eb = (E + 255) / 256;
    hist_kernel<<<eb, 256, 0, stream>>>(dst, counts, E);
    scan_kernel<<<1, 1024, 0, stream>>>(counts, offsets, wpos, n);
    fill_kernel<<<eb, 256, 0, stream>>>(src, dst, wpos, csr_src, csr_eid, E);
    ereorder_kernel<<<(E * 4 + 255) / 256, 256, 0, stream>>>(csr_eid, (const float4*)eattr,
                                                             (float4*)eattr_csr, E * 4);

    for (int lyr = 0; lyr < NLAYERS; ++lyr) {
        agg_kernel<<<(n + 3) / 4, 256, 0, stream>>>(h16, h32, csr_src, eattr_csr, offsets,
                                                    We, be, z0, n);
        mlp_kernel<<<(n + 63) / 64, 256, 0, stream>>>(z0, h32, h16,
                                                      Wt + (size_t)(lyr * 2 + 0) * 16384,
                                                      Wt + (size_t)(lyr * 2 + 1) * 16384,
                                                      b1 + (size_t)lyr * HIDDEN,
                                                      b2 + (size_t)lyr * HIDDEN,
                                                      lng + (size_t)lyr * HIDDEN,
                                                      lnb + (size_t)lyr * HIDDEN,
                                                      n, lyr != NLAYERS - 1);
    }
}

// Round 6
// 495.518 us; speedup vs baseline: 1.6980x; 1.6980x over previous
//
#include <hip/hip_runtime.h>

#define HIDDEN 128
#define NLAYERS 4

typedef __attribute__((ext_vector_type(8))) short short8;
typedef __attribute__((ext_vector_type(4))) float f32x4;

__device__ __forceinline__ ushort f2bf(float f) {
    uint x = __builtin_bit_cast(uint, f);
    return (ushort)((x + 0x7fffu + ((x >> 16) & 1u)) >> 16);
}
__device__ __forceinline__ float bf2f(ushort u) {
    uint x = ((uint)u) << 16;
    return __builtin_bit_cast(float, x);
}
__device__ __forceinline__ float bflo(uint u) {
    return __builtin_bit_cast(float, u << 16);
}
__device__ __forceinline__ float bfhi(uint u) {
    return __builtin_bit_cast(float, u & 0xffff0000u);
}

// ---------------- CSR build ----------------

__global__ void hist_kernel(const int* __restrict__ dst, int* __restrict__ counts, int E) {
    int e = blockIdx.x * blockDim.x + threadIdx.x;
    if (e < E) atomicAdd(&counts[dst[e]], 1);
}

// single-block scan, 4 elements/thread (4096/chunk)
__global__ __launch_bounds__(1024) void scan_kernel(const int* __restrict__ counts,
                                                    int* __restrict__ offsets,
                                                    int* __restrict__ wpos, int n) {
    __shared__ int wsum[16];
    __shared__ int carry_s;
    const int t = threadIdx.x, wv = t >> 6, ln = t & 63;
    if (t == 0) carry_s = 0;
    __syncthreads();
    for (int base = 0; base < n; base += 4096) {
        const int i = base + t * 4;
        int4 c = {0, 0, 0, 0};
        if (i + 3 < n) {
            c = *(const int4*)(counts + i);
        } else {
            if (i < n)     c.x = counts[i];
            if (i + 1 < n) c.y = counts[i + 1];
            if (i + 2 < n) c.z = counts[i + 2];
            if (i + 3 < n) c.w = counts[i + 3];
        }
        const int tsum = c.x + c.y + c.z + c.w;
        int s = tsum;
#pragma unroll
        for (int off = 1; off < 64; off <<= 1) {
            int x = __shfl_up(s, off, 64);
            if (ln >= off) s += x;
        }
        if (ln == 63) wsum[wv] = s;
        __syncthreads();
        if (t < 16) {
            int x = wsum[t];
#pragma unroll
            for (int off = 1; off < 16; off <<= 1) {
                int y = __shfl_up(x, off, 16);
                if ((t & 15) >= off) x += y;
            }
            wsum[t] = x;
        }
        __syncthreads();
        const int wbase = (wv ? wsum[wv - 1] : 0) + carry_s;
        const int excl = wbase + s - tsum;
        int4 o;
        o.x = excl;
        o.y = excl + c.x;
        o.z = o.y + c.y;
        o.w = o.z + c.z;
        if (i + 3 < n) {
            *(int4*)(offsets + i) = o;
            *(int4*)(wpos + i) = o;
        } else {
            if (i < n)     { offsets[i] = o.x;     wpos[i] = o.x; }
            if (i + 1 < n) { offsets[i + 1] = o.y; wpos[i + 1] = o.y; }
            if (i + 2 < n) { offsets[i + 2] = o.z; wpos[i + 2] = o.z; }
            if (i + 3 < n) { offsets[i + 3] = o.w; wpos[i + 3] = o.w; }
        }
        __syncthreads();
        if (t == 0) carry_s += wsum[15];
        __syncthreads();
    }
    if (t == 0) offsets[n] = carry_s;
}

__global__ void fill_kernel(const int* __restrict__ src, const int* __restrict__ dst,
                            int* __restrict__ wpos, int* __restrict__ csr_src,
                            int* __restrict__ csr_eid, int E) {
    int e = blockIdx.x * blockDim.x + threadIdx.x;
    if (e < E) {
        int d = dst[e];
        int p = atomicAdd(&wpos[d], 1);
        csr_src[p] = src[e];
        csr_eid[p] = e;
    }
}

// ---------------- init / weight prep ----------------

__global__ void h16init_kernel(const float* __restrict__ x, ushort* __restrict__ h16, int total4) {
    int i = blockIdx.x * blockDim.x + threadIdx.x;
    if (i < total4) {
        float4 v = ((const float4*)x)[i];
        uint2 o;
        o.x = (uint)f2bf(v.x) | ((uint)f2bf(v.y) << 16);
        o.y = (uint)f2bf(v.z) | ((uint)f2bf(v.w) << 16);
        ((uint2*)h16)[i] = o;
    }
}

__global__ void wconv_kernel(const float* __restrict__ W1, const float* __restrict__ W2,
                             ushort* __restrict__ Wt) {
    int i = blockIdx.x * blockDim.x + threadIdx.x;  // < 4*2*128*128
    int l = i >> 15;
    int m = (i >> 14) & 1;
    int nn = (i >> 7) & 127;
    int kk = i & 127;
    const float* W = m ? W2 : W1;
    Wt[i] = f2bf(W[l * 16384 + kk * 128 + nn]);
}

#define EA_FMA16(q0, q1, q2, q3)                                          \
    m0 = fmaf(q0.x, wec[0].x, m0);  m1 = fmaf(q0.x, wec[0].y, m1);        \
    m0 = fmaf(q0.y, wec[1].x, m0);  m1 = fmaf(q0.y, wec[1].y, m1);        \
    m0 = fmaf(q0.z, wec[2].x, m0);  m1 = fmaf(q0.z, wec[2].y, m1);        \
    m0 = fmaf(q0.w, wec[3].x, m0);  m1 = fmaf(q0.w, wec[3].y, m1);        \
    m0 = fmaf(q1.x, wec[4].x, m0);  m1 = fmaf(q1.x, wec[4].y, m1);        \
    m0 = fmaf(q1.y, wec[5].x, m0);  m1 = fmaf(q1.y, wec[5].y, m1);        \
    m0 = fmaf(q1.z, wec[6].x, m0);  m1 = fmaf(q1.z, wec[6].y, m1);        \
    m0 = fmaf(q1.w, wec[7].x, m0);  m1 = fmaf(q1.w, wec[7].y, m1);        \
    m0 = fmaf(q2.x, wec[8].x, m0);  m1 = fmaf(q2.x, wec[8].y, m1);        \
    m0 = fmaf(q2.y, wec[9].x, m0);  m1 = fmaf(q2.y, wec[9].y, m1);        \
    m0 = fmaf(q2.z, wec[10].x, m0); m1 = fmaf(q2.z, wec[10].y, m1);       \
    m0 = fmaf(q2.w, wec[11].x, m0); m1 = fmaf(q2.w, wec[11].y, m1);       \
    m0 = fmaf(q3.x, wec[12].x, m0); m1 = fmaf(q3.x, wec[12].y, m1);       \
    m0 = fmaf(q3.y, wec[13].x, m0); m1 = fmaf(q3.y, wec[13].y, m1);       \
    m0 = fmaf(q3.z, wec[14].x, m0); m1 = fmaf(q3.z, wec[14].y, m1);       \
    m0 = fmaf(q3.w, wec[15].x, m0); m1 = fmaf(q3.w, wec[15].y, m1)

// ---------------- ea precompute (CSR order) ----------------
__global__ __launch_bounds__(256) void ea_kernel(const int* __restrict__ csr_eid,
                                                 const float* __restrict__ edge_attr,
                                                 const float* __restrict__ We,
                                                 const float* __restrict__ be,
                                                 ushort* __restrict__ ea_csr, int E) {
    __shared__ int eids[256];
    __shared__ float4 ear[256][4];
    const int t = threadIdx.x, l = t & 63, w = t >> 6;
    const int c0 = l * 2;
    float2 wec[16];
#pragma unroll
    for (int k = 0; k < 16; ++k) wec[k] = *(const float2*)(We + k * HIDDEN + c0);
    const float2 bec = *(const float2*)(be + c0);
    const int p0 = blockIdx.x * 256;

    eids[t] = (p0 + t < E) ? csr_eid[p0 + t] : 0;
    __syncthreads();
#pragma unroll
    for (int k = 0; k < 4; ++k) {
        int e = (t >> 2) + k * 64;
        int part = t & 3;
        if (p0 + e < E)
            ear[e][part] = ((const float4*)edge_attr)[(size_t)eids[e] * 4 + part];
    }
    __syncthreads();

    for (int j = 0; j < 64; ++j) {
        int e = w * 64 + j;
        int p = p0 + e;
        if (p >= E) break;
        float4 q0 = ear[e][0], q1 = ear[e][1], q2 = ear[e][2], q3 = ear[e][3];
        float m0 = bec.x, m1 = bec.y;
        EA_FMA16(q0, q1, q2, q3);
        uint out = (uint)f2bf(m0) | ((uint)f2bf(m1) << 16);
        *(uint*)(ea_csr + (size_t)p * HIDDEN + c0) = out;
    }
}

// ---------------- aggregation: wave/node, 16-edge chunk fully hoisted to registers ----------------
// group g (16 lanes) owns edges B+g, B+g+4, B+g+8, B+g+12; lane q = 8 channels (uint4)
__global__ __launch_bounds__(256) void agg_kernel(const ushort* __restrict__ h16,
                                                  const float* __restrict__ h32,
                                                  const int* __restrict__ csr_src,
                                                  const ushort* __restrict__ ea_csr,
                                                  const int* __restrict__ offsets,
                                                  ushort* __restrict__ z0, int n) {
    const int v = blockIdx.x * 4 + (threadIdx.x >> 6);
    if (v >= n) return;
    const int l = threadIdx.x & 63;
    const int g = l >> 4, q = l & 15;

    const int e0 = offsets[v], e1 = offsets[v + 1];
    float acc[8];
#pragma unroll
    for (int i = 0; i < 8; ++i) acc[i] = 0.f;

    for (int B = e0; B < e1; B += 16) {
        // ---- load phase: everything for 16 edges into registers ----
        int ec[4];
        float vm[4];
#pragma unroll
        for (int j = 0; j < 4; ++j) {
            const int e = B + g + j * 4;
            vm[j] = (e < e1) ? 1.f : 0.f;
            ec[j] = (e < e1) ? e : (e1 - 1);
        }
        int sj[4];
#pragma unroll
        for (int j = 0; j < 4; ++j) sj[j] = csr_src[ec[j]];
        uint4 ev[4];
#pragma unroll
        for (int j = 0; j < 4; ++j)
            ev[j] = *(const uint4*)(ea_csr + (size_t)ec[j] * HIDDEN + q * 8);
        uint4 hv[4];
#pragma unroll
        for (int j = 0; j < 4; ++j)
            hv[j] = *(const uint4*)(h16 + (size_t)sj[j] * HIDDEN + q * 8);

        // ---- compute phase (pure VALU) ----
#pragma unroll
        for (int j = 0; j < 4; ++j) {
#define ACC2(i, ue, uh)                                                   \
            {                                                             \
                float s0 = bflo(ue) + bflo(uh);                           \
                float s1 = bfhi(ue) + bfhi(uh);                           \
                acc[2*(i)]   = fmaf(vm[j], fmaxf(s0, 0.f), acc[2*(i)]);   \
                acc[2*(i)+1] = fmaf(vm[j], fmaxf(s1, 0.f), acc[2*(i)+1]); \
            }
            ACC2(0, ev[j].x, hv[j].x)
            ACC2(1, ev[j].y, hv[j].y)
            ACC2(2, ev[j].z, hv[j].z)
            ACC2(3, ev[j].w, hv[j].w)
#undef ACC2
        }
    }

    // reduce across the 4 groups
#pragma unroll
    for (int i = 0; i < 8; ++i) {
        acc[i] += __shfl_xor(acc[i], 16, 64);
        acc[i] += __shfl_xor(acc[i], 32, 64);
    }

    if (g == 0) {
        const float* hp = h32 + (size_t)v * HIDDEN + q * 8;
        const float4 h0 = *(const float4*)hp;
        const float4 h1 = *(const float4*)(hp + 4);
        uint4 o;
        o.x = (uint)f2bf(h0.x + acc[0]) | ((uint)f2bf(h0.y + acc[1]) << 16);
        o.y = (uint)f2bf(h0.z + acc[2]) | ((uint)f2bf(h0.w + acc[3]) << 16);
        o.z = (uint)f2bf(h1.x + acc[4]) | ((uint)f2bf(h1.y + acc[5]) << 16);
        o.w = (uint)f2bf(h1.z + acc[6]) | ((uint)f2bf(h1.w + acc[7]) << 16);
        *(uint4*)(z0 + (size_t)v * HIDDEN + q * 8) = o;
    }
}

// ---------------- fallback aggregation (recompute ea per edge) ----------------
__global__ __launch_bounds__(128) void agg_fb_kernel(const ushort* __restrict__ h16,
                                                     const float* __restrict__ h32,
                                                     const int* __restrict__ csr_src,
                                                     const int* __restrict__ csr_eid,
                                                     const float* __restrict__ edge_attr,
                                                     const int* __restrict__ offsets,
                                                     const float* __restrict__ We,
                                                     const float* __restrict__ be,
                                                     ushort* __restrict__ z0, int n) {
    const int v = blockIdx.x * 2 + (threadIdx.x >> 6);
    if (v >= n) return;
    const int t = threadIdx.x & 63;
    const int c0 = t * 2;
    float2 wec[16];
#pragma unroll
    for (int k = 0; k < 16; ++k) wec[k] = *(const float2*)(We + k * HIDDEN + c0);
    const float2 bec = *(const float2*)(be + c0);

    const int e0 = offsets[v], e1 = offsets[v + 1];
    float a0 = 0.f, a1 = 0.f;
    for (int j = e0; j < e1; ++j) {
        int se = csr_src[j], eid = csr_eid[j];
        const float4* ea4 = (const float4*)(edge_attr + (size_t)eid * 16);
        float4 q0 = ea4[0], q1 = ea4[1], q2 = ea4[2], q3 = ea4[3];
        float m0 = bec.x, m1 = bec.y;
        EA_FMA16(q0, q1, q2, q3);
        uint hh = *(const uint*)(h16 + (size_t)se * HIDDEN + c0);
        a0 += fmaxf(m0 + bf2f((ushort)(hh & 0xffffu)), 0.f);
        a1 += fmaxf(m1 + bf2f((ushort)(hh >> 16)), 0.f);
    }
    const float2 hv = *(const float2*)(h32 + (size_t)v * HIDDEN + c0);
    uint out = (uint)f2bf(hv.x + a0) | ((uint)f2bf(hv.y + a1) << 16);
    *(uint*)(z0 + (size_t)v * HIDDEN + c0) = out;
}

// ---------------- fused MFMA MLP + in-register LayerNorm + residual ----------------
__global__ __launch_bounds__(256, 3) void mlp_kernel(const ushort* __restrict__ z0,
                                                     float* __restrict__ h32,
                                                     ushort* __restrict__ h16,
                                                     const ushort* __restrict__ W1t,
                                                     const ushort* __restrict__ W2t,
                                                     const float* __restrict__ b1,
                                                     const float* __restrict__ b2,
                                                     const float* __restrict__ lng,
                                                     const float* __restrict__ lnb,
                                                     int n, int write_h16) {
    __shared__ char smem[49152];  // [0,32K): weights (swizzled bf16) ; [32K,48K): act
    const int t = threadIdx.x, l = t & 63, w = t >> 6;
    const int lm = l & 15, lg = l >> 4;
    const int r0 = blockIdx.x * 64;

#pragma unroll
    for (int j = 0; j < 8; ++j) {
        int idx = t + j * 256;
        int byte = (idx * 16) ^ (((idx >> 4) & 7) << 4);
        *(short8*)(smem + byte) = *(const short8*)(W1t + idx * 8);
    }

    float b1v[8], b2v[8], lngv[8], lnbv[8];
#pragma unroll
    for (int nt = 0; nt < 8; ++nt) {
        int col = nt * 16 + lm;
        b1v[nt] = b1[col]; b2v[nt] = b2[col];
        lngv[nt] = lng[col]; lnbv[nt] = lnb[col];
    }

    short8 a[4];
    {
        int arow = r0 + w * 16 + lm;
        if (arow >= n) arow = n - 1;
        const ushort* zp = z0 + (size_t)arow * HIDDEN + lg * 8;
#pragma unroll
        for (int kk = 0; kk < 4; ++kk) a[kk] = *(const short8*)(zp + kk * 32);
    }
    __syncthreads();

    f32x4 acc[8];
#pragma unroll
    for (int nt = 0; nt < 8; ++nt) {
        f32x4 c = {0.f, 0.f, 0.f, 0.f};
#pragma unroll
        for (int kk = 0; kk < 4; ++kk) {
            int nrow = nt * 16 + lm;
            int byte = (nrow * 256 + kk * 64 + lg * 16) ^ ((nrow & 7) << 4);
            short8 b = *(const short8*)(smem + byte);
            c = __builtin_amdgcn_mfma_f32_16x16x32_bf16(a[kk], b, c, 0, 0, 0);
        }
        acc[nt] = c;
    }

#pragma unroll
    for (int nt = 0; nt < 8; ++nt) {
        int col = nt * 16 + lm;
#pragma unroll
        for (int j = 0; j < 4; ++j) {
            int rw = w * 16 + lg * 4 + j;
            int byte = (rw * 256 + col * 2) ^ ((rw & 7) << 4);
            *(ushort*)(smem + 32768 + byte) = f2bf(fmaxf(acc[nt][j] + b1v[nt], 0.f));
        }
    }
    __syncthreads();

#pragma unroll
    for (int j = 0; j < 8; ++j) {
        int idx = t + j * 256;
        int byte = (idx * 16) ^ (((idx >> 4) & 7) << 4);
        *(short8*)(smem + byte) = *(const short8*)(W2t + idx * 8);
    }
    short8 a2[4];
    {
        int rw = w * 16 + lm;
#pragma unroll
        for (int kk = 0; kk < 4; ++kk) {
            int byte = (rw * 256 + kk * 64 + lg * 16) ^ ((rw & 7) << 4);
            a2[kk] = *(const short8*)(smem + 32768 + byte);
        }
    }
    __syncthreads();

    f32x4 acc2[8];
#pragma unroll
    for (int nt = 0; nt < 8; ++nt) {
        f32x4 c = {0.f, 0.f, 0.f, 0.f};
#pragma unroll
        for (int kk = 0; kk < 4; ++kk) {
            int nrow = nt * 16 + lm;
            int byte = (nrow * 256 + kk * 64 + lg * 16) ^ ((nrow & 7) << 4);
            short8 b = *(const short8*)(smem + byte);
            c = __builtin_amdgcn_mfma_f32_16x16x32_bf16(a2[kk], b, c, 0, 0, 0);
        }
        acc2[nt] = c;
    }

    float val[8][4];
#pragma unroll
    for (int nt = 0; nt < 8; ++nt)
#pragma unroll
        for (int j = 0; j < 4; ++j) val[nt][j] = acc2[nt][j] + b2v[nt];

    float mu[4], rs[4];
#pragma unroll
    for (int j = 0; j < 4; ++j) {
        float s = 0.f;
#pragma unroll
        for (int nt = 0; nt < 8; ++nt) s += val[nt][j];
        s += __shfl_xor(s, 1, 64); s += __shfl_xor(s, 2, 64);
        s += __shfl_xor(s, 4, 64); s += __shfl_xor(s, 8, 64);
        mu[j] = s * (1.f / 128.f);
        float d2 = 0.f;
#pragma unroll
        for (int nt = 0; nt < 8; ++nt) {
            float d = val[nt][j] - mu[j];
            d2 = fmaf(d, d, d2);
        }
        d2 += __shfl_xor(d2, 1, 64); d2 += __shfl_xor(d2, 2, 64);
        d2 += __shfl_xor(d2, 4, 64); d2 += __shfl_xor(d2, 8, 64);
        rs[j] = rsqrtf(d2 * (1.f / 128.f) + 1e-5f);
    }

#pragma unroll
    for (int j = 0; j < 4; ++j) {
        int grow = r0 + w * 16 + lg * 4 + j;
        if (grow < n) {
#pragma unroll
            for (int nt = 0; nt < 8; ++nt) {
                int col = nt * 16 + lm;
                size_t o = (size_t)grow * HIDDEN + col;
                float y = fmaxf((val[nt][j] - mu[j]) * rs[j] * lngv[nt] + lnbv[nt], 0.f) + h32[o];
                h32[o] = y;
                if (write_h16) h16[o] = f2bf(y);
            }
        }
    }
}

// ---------------- launch ----------------

extern "C" void kernel_launch(void* const* d_in, const int* in_sizes, int n_in,
                              void* d_out, int out_size, void* d_ws, size_t ws_size,
                              hipStream_t stream) {
    const float* x     = (const float*)d_in[0];
    const int*   ei    = (const int*)d_in[2];
    const float* eattr = (const float*)d_in[3];
    const float* We    = (const float*)d_in[4];
    const float* be    = (const float*)d_in[5];
    const float* W1    = (const float*)d_in[6];
    const float* b1    = (const float*)d_in[7];
    const float* W2    = (const float*)d_in[8];
    const float* b2    = (const float*)d_in[9];
    const float* lng   = (const float*)d_in[10];
    const float* lnb   = (const float*)d_in[11];
    float* h32 = (float*)d_out;

    const int n = in_sizes[0] / HIDDEN;
    const int E = in_sizes[2] / 2;
    const int* src = ei;
    const int* dst = ei + E;

    size_t off = 0;
    auto take = [&](size_t bytes) {
        void* p = (char*)d_ws + off;
        off += (bytes + 255) & ~(size_t)255;
        return p;
    };
    ushort* z0      = (ushort*)take((size_t)n * HIDDEN * 2);
    ushort* h16     = (ushort*)take((size_t)n * HIDDEN * 2);
    ushort* Wt      = (ushort*)take((size_t)NLAYERS * 2 * HIDDEN * HIDDEN * 2);
    int*    counts  = (int*)take((size_t)n * 4);
    int*    offsets = (int*)take(((size_t)n + 1) * 4);
    int*    wpos    = (int*)take((size_t)n * 4);
    int*    csr_src = (int*)take((size_t)E * 4);
    int*    csr_eid = (int*)take((size_t)E * 4);
    const size_t ea_bytes = (size_t)E * HIDDEN * 2;
    const bool use_ea = (off + ea_bytes) <= ws_size;
    ushort* ea_csr = use_ea ? (ushort*)take(ea_bytes) : nullptr;

    hipMemcpyAsync(h32, x, (size_t)n * HIDDEN * 4, hipMemcpyDeviceToDevice, stream);
    h16init_kernel<<<((n * HIDDEN / 4) + 255) / 256, 256, 0, stream>>>(x, h16, n * HIDDEN / 4);
    wconv_kernel<<<(NLAYERS * 2 * HIDDEN * HIDDEN) / 256, 256, 0, stream>>>(W1, W2, Wt);

    hipMemsetAsync(counts, 0, (size_t)n * 4, stream);
    int eb = (E + 255) / 256;
    hist_kernel<<<eb, 256, 0, stream>>>(dst, counts, E);
    scan_kernel<<<1, 1024, 0, stream>>>(counts, offsets, wpos, n);
    fill_kernel<<<eb, 256, 0, stream>>>(src, dst, wpos, csr_src, csr_eid, E);
    if (use_ea)
        ea_kernel<<<(E + 255) / 256, 256, 0, stream>>>(csr_eid, eattr, We, be, ea_csr, E);

    for (int lyr = 0; lyr < NLAYERS; ++lyr) {
        if (use_ea)
            agg_kernel<<<(n + 3) / 4, 256, 0, stream>>>(h16, h32, csr_src, ea_csr, offsets, z0, n);
        else
            agg_fb_kernel<<<(n + 1) / 2, 128, 0, stream>>>(h16, h32, csr_src, csr_eid, eattr,
                                                           offsets, We, be, z0, n);
        mlp_kernel<<<(n + 63) / 64, 256, 0, stream>>>(z0, h32, h16,
                                                      Wt + (size_t)(lyr * 2 + 0) * 16384,
                                                      Wt + (size_t)(lyr * 2 + 1) * 16384,
                                                      b1 + (size_t)lyr * HIDDEN,
                                                      b2 + (size_t)lyr * HIDDEN,
                                                      lng + (size_t)lyr * HIDDEN,
                                                      lnb + (size_t)lyr * HIDDEN,
                                                      n, lyr != NLAYERS - 1);
    }
}